// Round 4
// baseline (9006.237 us; speedup 1.0000x reference)
//
#include <hip/hip_runtime.h>
#include <math.h>

#define BB 128
#define RR 512
#define NSTEP 255

typedef __attribute__((ext_vector_type(8))) __bf16 bf16x8;
typedef __attribute__((ext_vector_type(4))) float f32x4;

__device__ __forceinline__ bf16x8 ld8(const ushort* p) {
  return *reinterpret_cast<const bf16x8*>(p);
}
__device__ __forceinline__ ushort bf16r(float x) {
  unsigned u = __float_as_uint(x);
  u += 0x7fffu + ((u >> 16) & 1u);
  return (ushort)(u >> 16);
}
__device__ __forceinline__ float fsig(float x) { return 1.0f / (1.0f + __expf(-x)); }
__device__ __forceinline__ float ftanh(float x) {
  float e = __expf(-2.0f * fabsf(x));
  float r = (1.0f - e) / (1.0f + e);
  return copysignf(r, x);
}

// Persistent recurrent kernel.
// units: 0=fwd L0, 1=bwd L0, 2=fwd L1, 3=bwd L1.
// 128 blocks x 128 threads: block = (unit, j-tile of 16 cols), covers all 128
// batch rows via 2 waves x 4 m-frags (m64 each). Weights live in LDS (bf16,
// XOR-swizzled) for the whole run. hist[u] = (256,128,512) bf16, slot 0 = 0,
// h(s) at slot s+1 (write-once -> race-free). Sync: per-unit arrive counters;
// L1 at step s waits cnt[u-2] >= 32*(s+1) (h0[s] ready) and cnt[u] >= 32*s.
struct PP {
  const ushort* gtb;     // (256,128,64) bf16
  const ushort* xpad;    // (256,128,96) bf16
  const float* Wh[4];    // (1536,512) fp32
  const float* Wi[4];    // u0:(1536,64) u1:(1536,65->use 65? no: staged cols<xd) u2,3:(1536,512)
  const float* bi[4];
  const float* bh[4];
  ushort* hist[4];       // 4 x (256,128,512) bf16
  int* cnt;              // 4 counters at stride 64 ints
  int xd1;               // 65 (true cols of bWi0) -- staged into 96-wide LDS rows
};

__global__ __launch_bounds__(128, 1)
void persist(PP p) {
  const int bid = blockIdx.x;
  const int u = bid >> 5;            // 4 units x 32 j-tiles
  const int jb = bid & 31;
  const int j0 = jb * 16;
  const bool l1 = (u >= 2);
  const int tid = threadIdx.x;
  const int wave = tid >> 6, lane = tid & 63;
  const int lr = lane & 15, kqi = lane >> 4;
  const int kq = kqi * 8;
  const int m0w = wave * 64;
  const int mask = (lr & 7) << 4;
  const int col = j0 + lr;

  __shared__ ushort wl[49152];   // 96KB: Wh (48KB) + Wi_l1 (48KB) / wilds_l0 (12KB)

  // ---- stage Wh: LDS row = g*16+jj <-> global row g*512+j0+jj; 512 cols ----
  for (int c = tid; c < 3072; c += 128) {           // 8-col chunks
    int row = c >> 6, ci = c & 63;
    int jj = row & 15, g = row >> 4;
    const float* src = p.Wh[u] + ((size_t)(g * 512 + j0 + jj) * 512 + ci * 8);
    float4 f0 = *(const float4*)(src);
    float4 f1 = *(const float4*)(src + 4);
    uint4 v;
    v.x = bf16r(f0.x) | ((unsigned)bf16r(f0.y) << 16);
    v.y = bf16r(f0.z) | ((unsigned)bf16r(f0.w) << 16);
    v.z = bf16r(f1.x) | ((unsigned)bf16r(f1.y) << 16);
    v.w = bf16r(f1.z) | ((unsigned)bf16r(f1.w) << 16);
    int a = (row * 1024 + ci * 16) ^ ((jj & 7) << 4);
    *reinterpret_cast<uint4*>((char*)wl + a) = v;
  }
  if (l1) {
    // Wi (512 cols) at byte base 49152
    for (int c = tid; c < 3072; c += 128) {
      int row = c >> 6, ci = c & 63;
      int jj = row & 15, g = row >> 4;
      const float* src = p.Wi[u] + ((size_t)(g * 512 + j0 + jj) * 512 + ci * 8);
      float4 f0 = *(const float4*)(src);
      float4 f1 = *(const float4*)(src + 4);
      uint4 v;
      v.x = bf16r(f0.x) | ((unsigned)bf16r(f0.y) << 16);
      v.y = bf16r(f0.z) | ((unsigned)bf16r(f0.w) << 16);
      v.z = bf16r(f1.x) | ((unsigned)bf16r(f1.y) << 16);
      v.w = bf16r(f1.z) | ((unsigned)bf16r(f1.w) << 16);
      int a = 49152 + ((row * 1024 + ci * 16) ^ ((jj & 7) << 4));
      *reinterpret_cast<uint4*>((char*)wl + a) = v;
    }
  } else {
    // wilds: 48 rows x 128 cols (256B stride) at byte base 49152; fill cols<xd
    const int xd = (u == 0) ? 64 : 65;       // true global col count
    const int xds = (u == 0) ? 64 : 96;      // staged col count (zero-pad 65->96)
    for (int c = tid; c < 48 * (xds / 8); c += 128) {
      int cols8 = xds / 8;
      int row = c / cols8, ci = c - row * cols8;
      int jj = row & 15, g = row >> 4;
      const float* src = p.Wi[u] + ((size_t)(g * 512 + j0 + jj) * xd + ci * 8);
      float f[8];
      #pragma unroll
      for (int e = 0; e < 8; ++e) {
        int cc = ci * 8 + e;
        f[e] = (cc < xd) ? src[e] : 0.0f;
      }
      uint4 v;
      v.x = bf16r(f[0]) | ((unsigned)bf16r(f[1]) << 16);
      v.y = bf16r(f[2]) | ((unsigned)bf16r(f[3]) << 16);
      v.z = bf16r(f[4]) | ((unsigned)bf16r(f[5]) << 16);
      v.w = bf16r(f[6]) | ((unsigned)bf16r(f[7]) << 16);
      int a = 49152 + ((row * 256 + ci * 16) ^ ((jj & 7) << 4));
      *reinterpret_cast<uint4*>((char*)wl + a) = v;
    }
  }
  const float biN = p.bi[u][col + 1024];
  const float bhN = p.bh[u][col + 1024];
  const float r0 = p.bi[u][col] + p.bh[u][col];
  const float z0 = p.bi[u][col + 512] + p.bh[u][col + 512];
  __syncthreads();

  f32x4 hp[4] = {};
  ushort* histS = p.hist[u];
  const ushort* histP = l1 ? p.hist[u - 2] : (const ushort*)0;
  int* cs = p.cnt + u * 64;
  int* cp = l1 ? p.cnt + (u - 2) * 64 : (int*)0;
  const int wb = lr * 1024 + kq * 2;

  for (int s = 0; s < NSTEP; ++s) {
    if (tid == 0) {
      int tgt = 32 * s;
      while (__hip_atomic_load(cs, __ATOMIC_ACQUIRE, __HIP_MEMORY_SCOPE_AGENT) < tgt)
        __builtin_amdgcn_s_sleep(2);
      if (l1) {
        int tp = 32 * (s + 1);
        while (__hip_atomic_load(cp, __ATOMIC_ACQUIRE, __HIP_MEMORY_SCOPE_AGENT) < tp)
          __builtin_amdgcn_s_sleep(2);
      }
    }
    __syncthreads();

    f32x4 aR[4], aZ[4], aIN[4], aHN[4];
    #pragma unroll
    for (int mf = 0; mf < 4; ++mf) {
      aR[mf] = (f32x4){r0, r0, r0, r0};
      aZ[mf] = (f32x4){z0, z0, z0, z0};
      aIN[mf] = (f32x4){biN, biN, biN, biN};
      aHN[mf] = (f32x4){bhN, bhN, bhN, bhN};
    }

    const ushort* aS = histS + (size_t)s * 65536;
    if (l1) {
      const ushort* aP = histP + (size_t)(s + 1) * 65536;
      for (int kc = 0; kc < 512; kc += 32) {
        int o1 = (wb + kc * 2) ^ mask;
        bf16x8 wr = *(const bf16x8*)((const char*)wl + o1);
        bf16x8 wz = *(const bf16x8*)((const char*)wl + (o1 + 16384));
        bf16x8 wn = *(const bf16x8*)((const char*)wl + (o1 + 32768));
        bf16x8 vr = *(const bf16x8*)((const char*)wl + (o1 + 49152));
        bf16x8 vz = *(const bf16x8*)((const char*)wl + (o1 + 65536));
        bf16x8 vn = *(const bf16x8*)((const char*)wl + (o1 + 81920));
        #pragma unroll
        for (int mf = 0; mf < 4; ++mf) {
          bf16x8 a  = ld8(aS + (m0w + mf * 16 + lr) * 512 + kc + kq);
          bf16x8 a2 = ld8(aP + (m0w + mf * 16 + lr) * 512 + kc + kq);
          aR[mf]  = __builtin_amdgcn_mfma_f32_16x16x32_bf16(a,  wr, aR[mf], 0, 0, 0);
          aZ[mf]  = __builtin_amdgcn_mfma_f32_16x16x32_bf16(a,  wz, aZ[mf], 0, 0, 0);
          aHN[mf] = __builtin_amdgcn_mfma_f32_16x16x32_bf16(a,  wn, aHN[mf], 0, 0, 0);
          aR[mf]  = __builtin_amdgcn_mfma_f32_16x16x32_bf16(a2, vr, aR[mf], 0, 0, 0);
          aZ[mf]  = __builtin_amdgcn_mfma_f32_16x16x32_bf16(a2, vz, aZ[mf], 0, 0, 0);
          aIN[mf] = __builtin_amdgcn_mfma_f32_16x16x32_bf16(a2, vn, aIN[mf], 0, 0, 0);
        }
      }
    } else {
      for (int kc = 0; kc < 512; kc += 32) {
        int o1 = (wb + kc * 2) ^ mask;
        bf16x8 wr = *(const bf16x8*)((const char*)wl + o1);
        bf16x8 wz = *(const bf16x8*)((const char*)wl + (o1 + 16384));
        bf16x8 wn = *(const bf16x8*)((const char*)wl + (o1 + 32768));
        #pragma unroll
        for (int mf = 0; mf < 4; ++mf) {
          bf16x8 a = ld8(aS + (m0w + mf * 16 + lr) * 512 + kc + kq);
          aR[mf]  = __builtin_amdgcn_mfma_f32_16x16x32_bf16(a, wr, aR[mf], 0, 0, 0);
          aZ[mf]  = __builtin_amdgcn_mfma_f32_16x16x32_bf16(a, wz, aZ[mf], 0, 0, 0);
          aHN[mf] = __builtin_amdgcn_mfma_f32_16x16x32_bf16(a, wn, aHN[mf], 0, 0, 0);
        }
      }
      // input projection
      const int xd = (u == 0) ? 64 : 96;
      const ushort* x = (u == 0) ? p.gtb + (size_t)s * 8192
                                 : p.xpad + (size_t)(255 - s) * 12288;
      for (int kc = 0; kc < xd; kc += 32) {
        int o1 = 49152 + ((lr * 256 + kq * 2 + kc * 2) ^ mask);
        bf16x8 vr = *(const bf16x8*)((const char*)wl + o1);
        bf16x8 vz = *(const bf16x8*)((const char*)wl + (o1 + 4096));
        bf16x8 vn = *(const bf16x8*)((const char*)wl + (o1 + 8192));
        #pragma unroll
        for (int mf = 0; mf < 4; ++mf) {
          bf16x8 a = ld8(x + (m0w + mf * 16 + lr) * xd + kc + kq);
          aR[mf]  = __builtin_amdgcn_mfma_f32_16x16x32_bf16(a, vr, aR[mf], 0, 0, 0);
          aZ[mf]  = __builtin_amdgcn_mfma_f32_16x16x32_bf16(a, vz, aZ[mf], 0, 0, 0);
          aIN[mf] = __builtin_amdgcn_mfma_f32_16x16x32_bf16(a, vn, aIN[mf], 0, 0, 0);
        }
      }
    }

    ushort* ho = histS + (size_t)(s + 1) * 65536;
    #pragma unroll
    for (int mf = 0; mf < 4; ++mf) {
      #pragma unroll
      for (int q = 0; q < 4; ++q) {
        float r = fsig(aR[mf][q]);
        float z = fsig(aZ[mf][q]);
        float n = ftanh(fmaf(r, aHN[mf][q], aIN[mf][q]));
        float h = fmaf(z, hp[mf][q] - n, n);
        hp[mf][q] = h;
        int row = m0w + mf * 16 + kqi * 4 + q;
        ho[row * 512 + col] = bf16r(h);
      }
    }
    __threadfence();
    __syncthreads();
    if (tid == 0)
      __hip_atomic_fetch_add(cs, 1, __ATOMIC_RELEASE, __HIP_MEMORY_SCOPE_AGENT);
  }
}

// dec_t = relu([H, hb_used] @ dec_W^T + dec_b): M=255*128, N=512, K=1024
__global__ __launch_bounds__(256)
void dec_mfma(const ushort* __restrict__ Hsb, const ushort* __restrict__ Ssb,
              const ushort* __restrict__ decWb, const float* __restrict__ decb,
              ushort* __restrict__ dectb) {
  const int t  = blockIdx.x;
  const int nb = blockIdx.y;
  const int wave = threadIdx.x >> 6, lane = threadIdx.x & 63;
  const int lr = lane & 15, kq = (lane >> 4) * 8;
  const int mrow = wave * 32;
  f32x4 acc[2][4] = {};
  for (int kc = 0; kc < 1024; kc += 32) {
    if (kc >= 512 && t == 254) break;
    const ushort* abase = (kc < 512)
        ? Hsb + ((size_t)t * BB) * RR + kc
        : Ssb + ((size_t)(253 - t) * BB) * RR + (kc - 512);
    bf16x8 a[2];
    #pragma unroll
    for (int mi = 0; mi < 2; ++mi)
      a[mi] = ld8(abase + (mrow + mi * 16 + lr) * RR + kq);
    bf16x8 bw[4];
    #pragma unroll
    for (int ni = 0; ni < 4; ++ni)
      bw[ni] = ld8(decWb + (size_t)(nb * 64 + ni * 16 + lr) * 1024 + kc + kq);
    #pragma unroll
    for (int mi = 0; mi < 2; ++mi)
      #pragma unroll
      for (int ni = 0; ni < 4; ++ni)
        acc[mi][ni] = __builtin_amdgcn_mfma_f32_16x16x32_bf16(a[mi], bw[ni], acc[mi][ni], 0, 0, 0);
  }
  #pragma unroll
  for (int mi = 0; mi < 2; ++mi)
    #pragma unroll
    for (int ni = 0; ni < 4; ++ni)
      #pragma unroll
      for (int q = 0; q < 4; ++q) {
        int row = t * BB + mrow + mi * 16 + (lane >> 4) * 4 + q;
        int n = nb * 64 + ni * 16 + lr;
        float v = fmaxf(acc[mi][ni][q] + decb[n], 0.0f);
        dectb[(size_t)row * 512 + n] = bf16r(v);
      }
}

// mean = dec_t @ mean_W^T + mean_b; loss += (mean - gt[t+1])^2
__global__ __launch_bounds__(256)
void mean_loss_mfma(const ushort* __restrict__ dectb, const ushort* __restrict__ meanWb,
                    const float* __restrict__ meanb, const float* __restrict__ gt,
                    float* __restrict__ out) {
  const int t = blockIdx.x;
  const int wave = threadIdx.x >> 6, lane = threadIdx.x & 63;
  const int lr = lane & 15, kq = (lane >> 4) * 8;
  const int mrow = wave * 32;
  f32x4 acc[2][4] = {};
  for (int kc = 0; kc < 512; kc += 32) {
    bf16x8 a[2];
    #pragma unroll
    for (int mi = 0; mi < 2; ++mi)
      a[mi] = ld8(dectb + ((size_t)t * BB + mrow + mi * 16 + lr) * 512 + kc + kq);
    bf16x8 bw[4];
    #pragma unroll
    for (int ni = 0; ni < 4; ++ni)
      bw[ni] = ld8(meanWb + (size_t)(ni * 16 + lr) * 512 + kc + kq);
    #pragma unroll
    for (int mi = 0; mi < 2; ++mi)
      #pragma unroll
      for (int ni = 0; ni < 4; ++ni)
        acc[mi][ni] = __builtin_amdgcn_mfma_f32_16x16x32_bf16(a[mi], bw[ni], acc[mi][ni], 0, 0, 0);
  }
  float lsum = 0.0f;
  #pragma unroll
  for (int mi = 0; mi < 2; ++mi)
    #pragma unroll
    for (int ni = 0; ni < 4; ++ni)
      #pragma unroll
      for (int q = 0; q < 4; ++q) {
        int b = mrow + mi * 16 + (lane >> 4) * 4 + q;
        int y = ni * 16 + lr;
        float m = acc[mi][ni][q] + meanb[y];
        float d = m - gt[(((size_t)(t + 1)) * BB + b) * 64 + y];
        lsum = fmaf(d, d, lsum);
      }
  __shared__ float red[256];
  red[threadIdx.x] = lsum;
  __syncthreads();
  for (int s2 = 128; s2 > 0; s2 >>= 1) {
    if (threadIdx.x < s2) red[threadIdx.x] += red[threadIdx.x + s2];
    __syncthreads();
  }
  if (threadIdx.x == 0) atomicAdd(out, red[0] * (1.0f / 32640.0f));
}

__global__ __launch_bounds__(256)
void cvt_bf16(const float* __restrict__ s, ushort* __restrict__ d, int n) {
  for (int i = blockIdx.x * 256 + threadIdx.x; i < n; i += gridDim.x * 256)
    d[i] = bf16r(s[i]);
}

__global__ __launch_bounds__(256)
void cvt_bf16_pad(const float* __restrict__ s, ushort* __restrict__ d,
                  int rows, int sc, int dc) {
  int n = rows * dc;
  for (int i = blockIdx.x * 256 + threadIdx.x; i < n; i += gridDim.x * 256) {
    int r = i / dc, c = i - r * dc;
    d[i] = (c < sc) ? bf16r(s[r * sc + c]) : (ushort)0;
  }
}

extern "C" void kernel_launch(void* const* d_in, const int* in_sizes, int n_in,
                              void* d_out, int out_size, void* d_ws, size_t ws_size,
                              hipStream_t stream) {
  const float* data = (const float*)d_in[0];
  const float* gt   = (const float*)d_in[1];
  PP p;
  p.Wi[0] = (const float*)d_in[2];  p.Wh[0] = (const float*)d_in[3];
  p.bi[0] = (const float*)d_in[4];  p.bh[0] = (const float*)d_in[5];
  p.Wi[2] = (const float*)d_in[6];  p.Wh[2] = (const float*)d_in[7];
  p.bi[2] = (const float*)d_in[8];  p.bh[2] = (const float*)d_in[9];
  p.Wi[1] = (const float*)d_in[10]; p.Wh[1] = (const float*)d_in[11];
  p.bi[1] = (const float*)d_in[12]; p.bh[1] = (const float*)d_in[13];
  p.Wi[3] = (const float*)d_in[14]; p.Wh[3] = (const float*)d_in[15];
  p.bi[3] = (const float*)d_in[16]; p.bh[3] = (const float*)d_in[17];
  const float* decW  = (const float*)d_in[18];
  const float* decb  = (const float*)d_in[19];
  const float* meanW = (const float*)d_in[20];
  const float* meanb = (const float*)d_in[21];

  // ws: cnt(1KB) | hist[4] (4x33.55MB) | gtb | xpad | decWb | meanWb
  char* w = (char*)d_ws;
  int* cnt = (int*)w;                    w += 1024;
  ushort* hist[4];
  for (int u2 = 0; u2 < 4; ++u2) { hist[u2] = (ushort*)w; w += (size_t)256 * BB * RR * 2; }
  ushort* gtb    = (ushort*)w; w += (size_t)256 * BB * 64 * 2;
  ushort* xpad   = (ushort*)w; w += (size_t)256 * BB * 96 * 2;
  ushort* decWb  = (ushort*)w; w += (size_t)512 * 1024 * 2;
  ushort* meanWb = (ushort*)w; w += (size_t)64 * 512 * 2;
  ushort* dectb  = hist[0];   // aliased: hist0 dead once persistent kernel exits

  hipMemsetAsync(d_out, 0, sizeof(float), stream);
  hipMemsetAsync(cnt, 0, 1024, stream);
  for (int u2 = 0; u2 < 4; ++u2)
    hipMemsetAsync(hist[u2], 0, (size_t)BB * RR * 2, stream);   // slot 0 = zeros

  cvt_bf16<<<512, 256, 0, stream>>>(gt, gtb, 256 * BB * 64);
  cvt_bf16_pad<<<512, 256, 0, stream>>>(data, xpad, 256 * BB, 65, 96);
  cvt_bf16<<<256, 256, 0, stream>>>(decW, decWb, 512 * 1024);
  cvt_bf16<<<64, 256, 0, stream>>>(meanW, meanWb, 64 * 512);

  p.gtb = gtb; p.xpad = xpad;
  for (int u2 = 0; u2 < 4; ++u2) p.hist[u2] = hist[u2];
  p.cnt = cnt;
  p.xd1 = 65;

  persist<<<dim3(128), dim3(128), 0, stream>>>(p);

  dec_mfma<<<dim3(255, 8), dim3(256), 0, stream>>>(hist[2] + 65536, hist[3] + 65536,
                                                   decWb, decb, dectb);
  mean_loss_mfma<<<dim3(255), dim3(256), 0, stream>>>(dectb, meanWb, meanb, gt,
                                                      (float*)d_out);
}

// Round 5
// 6037.089 us; speedup vs baseline: 1.4918x; 1.4918x over previous
//
#include <hip/hip_runtime.h>
#include <math.h>

#define BB 128
#define RR 512
#define NSTEP 255

typedef __attribute__((ext_vector_type(8))) __bf16 bf16x8;
typedef __attribute__((ext_vector_type(4))) float f32x4;

__device__ __forceinline__ bf16x8 ld8(const ushort* p) {
  return *reinterpret_cast<const bf16x8*>(p);
}
__device__ __forceinline__ ushort bf16r(float x) {
  unsigned u = __float_as_uint(x);
  u += 0x7fffu + ((u >> 16) & 1u);
  return (ushort)(u >> 16);
}
__device__ __forceinline__ float fsig(float x) { return 1.0f / (1.0f + __expf(-x)); }
__device__ __forceinline__ float ftanh(float x) {
  float e = __expf(-2.0f * fabsf(x));
  float r = (1.0f - e) / (1.0f + e);
  return copysignf(r, x);
}

// Two-phase persistent recurrence.
// units: 0=fwd L0, 1=bwd L0, 2=fwd L1, 3=bwd L1.
// recur<0>: u0,u1 run all 255 steps (input projections from gt/data, small K).
// recur<2>: u2,u3 run all 255 steps (gi = h0[s] @ Wi read from finished hist).
// Per phase: 128 blocks = 2 units x 32 j-tiles(16 cols) x 2 m-halves(64 rows),
// 256 threads = 4 waves x m16. Weights bf16 in LDS in exact fragment order
// (idx*1024 + lane*16 -> conflict-free ds_read_b128). hist[u]: 256 slots of
// (128,512) bf16; slot 0 = zeros, h[s] at slot s+1 (write-once).
// Sync per step: 64 per-block flags/unit; wave0 polls all 64 with one RELAXED
// load + ballot, then ONE threadfence; producer: syncthreads -> threadfence ->
// relaxed flag store. (r4 lesson: ACQUIRE-per-poll invalidates XCD L2.)
struct RP {
  const ushort* gtb;     // (256,128,64) bf16
  const ushort* xpad;    // (256,128,96) bf16 (data padded 65->96)
  const float* Wh[4];    // (1536,512) fp32
  const float* Wi[4];    // u0:(1536,64) u1:(1536,65) u2,3:(1536,512) fp32
  const float* bi[4];
  const float* bh[4];
  ushort* hist[4];
  int* flags;            // [4][64]
};

template<int UBASE>
__global__ __launch_bounds__(256, 1)
void recur(RP p) {
  const int bid = blockIdx.x;
  const int u = UBASE + (bid >> 6);      // 2 units x 64 blocks
  const int sub = bid & 63;
  const int jb = sub >> 1;               // 32 j-tiles
  const int mh = sub & 1;                // 2 m-halves
  const int j0 = jb * 16;
  const bool l1 = (UBASE >= 2);
  const int tid = threadIdx.x;
  const int wave = tid >> 6, lane = tid & 63;
  const int lr = lane & 15, kqi = lane >> 4;
  const int kq = kqi * 8;
  const int m0 = mh * 64 + wave * 16;
  const int col = j0 + lr;

  // 96KB LDS: [0,48K) gh weight frags, [48K, ...) gi weight frags.
  // frag layout: idx = it*3 + g; byte addr = idx*1024 + lane*16.
  __shared__ ushort wl[49152];

  // ---- stage gh weights (48 idx x 64 lanes, one-time) ----
  {
    const float* Wh = p.Wh[u];
    for (int f = tid; f < 3072; f += 256) {
      int idx = f >> 6, l = f & 63;
      int it = idx / 3, g = idx - it * 3;
      const float* src = Wh + (size_t)(g * 512 + j0 + (l & 15)) * 512
                            + it * 32 + (l >> 4) * 8;
      float4 f0 = *(const float4*)src;
      float4 f1 = *(const float4*)(src + 4);
      uint4 v;
      v.x = bf16r(f0.x) | ((unsigned)bf16r(f0.y) << 16);
      v.y = bf16r(f0.z) | ((unsigned)bf16r(f0.w) << 16);
      v.z = bf16r(f1.x) | ((unsigned)bf16r(f1.y) << 16);
      v.w = bf16r(f1.z) | ((unsigned)bf16r(f1.w) << 16);
      *reinterpret_cast<uint4*>((char*)wl + idx * 1024 + l * 16) = v;
    }
  }
  // ---- stage gi weights ----
  const int xits = l1 ? 16 : (u == 0 ? 2 : 3);   // k-iters of 32
  const int xd   = l1 ? 512 : (u == 0 ? 64 : 65);  // true global cols
  const int xds  = l1 ? 512 : (u == 0 ? 64 : 96);  // input row stride
  {
    const float* Wi = p.Wi[u];
    for (int f = tid; f < xits * 3 * 64; f += 256) {
      int idx = f >> 6, l = f & 63;
      int it = idx / 3, g = idx - it * 3;
      const float* src = Wi + (size_t)(g * 512 + j0 + (l & 15)) * xd
                            + it * 32 + (l >> 4) * 8;
      float fv[8];
      #pragma unroll
      for (int e = 0; e < 8; ++e) {
        int cc = it * 32 + (l >> 4) * 8 + e;
        fv[e] = (cc < xd) ? src[e] : 0.0f;
      }
      uint4 v;
      v.x = bf16r(fv[0]) | ((unsigned)bf16r(fv[1]) << 16);
      v.y = bf16r(fv[2]) | ((unsigned)bf16r(fv[3]) << 16);
      v.z = bf16r(fv[4]) | ((unsigned)bf16r(fv[5]) << 16);
      v.w = bf16r(fv[6]) | ((unsigned)bf16r(fv[7]) << 16);
      *reinterpret_cast<uint4*>((char*)wl + 49152 + idx * 1024 + l * 16) = v;
    }
  }

  const float r0  = p.bi[u][col] + p.bh[u][col];
  const float z0  = p.bi[u][col + 512] + p.bh[u][col + 512];
  const float biN = p.bi[u][col + 1024];
  const float bhN = p.bh[u][col + 1024];
  __syncthreads();

  ushort* histU = p.hist[u];
  const ushort* histP = l1 ? p.hist[u - 2] : (const ushort*)0;
  int* fl = p.flags + u * 64;
  f32x4 hp = {0.0f, 0.0f, 0.0f, 0.0f};

  for (int s = 0; s < NSTEP; ++s) {
    if (s > 0) {
      if (tid < 64) {
        for (;;) {
          int v = __hip_atomic_load(fl + lane, __ATOMIC_RELAXED,
                                    __HIP_MEMORY_SCOPE_AGENT);
          if (__ballot(v >= s) == ~0ull) break;
          __builtin_amdgcn_s_sleep(1);
        }
        __threadfence();   // one acquire-side fence per step
      }
    }
    __syncthreads();

    f32x4 aR  = {r0, r0, r0, r0};
    f32x4 aZ  = {z0, z0, z0, z0};
    f32x4 aIN = {biN, biN, biN, biN};
    f32x4 aHN = {bhN, bhN, bhN, bhN};

    const ushort* aS = histU + (size_t)s * 65536 + (m0 + lr) * 512 + kq;
    if (l1) {
      const ushort* aP = histP + (size_t)(s + 1) * 65536 + (m0 + lr) * 512 + kq;
      #pragma unroll 4
      for (int it = 0; it < 16; ++it) {
        bf16x8 a  = ld8(aS + it * 32);
        bf16x8 a2 = ld8(aP + it * 32);
        const char* wb = (const char*)wl + it * 3072 + lane * 16;
        bf16x8 wr = *(const bf16x8*)(wb);
        bf16x8 wz = *(const bf16x8*)(wb + 1024);
        bf16x8 wn = *(const bf16x8*)(wb + 2048);
        bf16x8 vr = *(const bf16x8*)(wb + 49152);
        bf16x8 vz = *(const bf16x8*)(wb + 50176);
        bf16x8 vn = *(const bf16x8*)(wb + 51200);
        aR  = __builtin_amdgcn_mfma_f32_16x16x32_bf16(a,  wr, aR, 0, 0, 0);
        aZ  = __builtin_amdgcn_mfma_f32_16x16x32_bf16(a,  wz, aZ, 0, 0, 0);
        aHN = __builtin_amdgcn_mfma_f32_16x16x32_bf16(a,  wn, aHN, 0, 0, 0);
        aR  = __builtin_amdgcn_mfma_f32_16x16x32_bf16(a2, vr, aR, 0, 0, 0);
        aZ  = __builtin_amdgcn_mfma_f32_16x16x32_bf16(a2, vz, aZ, 0, 0, 0);
        aIN = __builtin_amdgcn_mfma_f32_16x16x32_bf16(a2, vn, aIN, 0, 0, 0);
      }
    } else {
      #pragma unroll 4
      for (int it = 0; it < 16; ++it) {
        bf16x8 a = ld8(aS + it * 32);
        const char* wb = (const char*)wl + it * 3072 + lane * 16;
        bf16x8 wr = *(const bf16x8*)(wb);
        bf16x8 wz = *(const bf16x8*)(wb + 1024);
        bf16x8 wn = *(const bf16x8*)(wb + 2048);
        aR  = __builtin_amdgcn_mfma_f32_16x16x32_bf16(a, wr, aR, 0, 0, 0);
        aZ  = __builtin_amdgcn_mfma_f32_16x16x32_bf16(a, wz, aZ, 0, 0, 0);
        aHN = __builtin_amdgcn_mfma_f32_16x16x32_bf16(a, wn, aHN, 0, 0, 0);
      }
      const ushort* x = (u == 0) ? p.gtb + (size_t)s * BB * 64
                                 : p.xpad + (size_t)(255 - s) * BB * 96;
      const ushort* xA = x + (m0 + lr) * xds + kq;
      for (int it = 0; it < xits; ++it) {
        bf16x8 a = ld8(xA + it * 32);
        const char* wb = (const char*)wl + 49152 + it * 3072 + lane * 16;
        bf16x8 vr = *(const bf16x8*)(wb);
        bf16x8 vz = *(const bf16x8*)(wb + 1024);
        bf16x8 vn = *(const bf16x8*)(wb + 2048);
        aR  = __builtin_amdgcn_mfma_f32_16x16x32_bf16(a, vr, aR, 0, 0, 0);
        aZ  = __builtin_amdgcn_mfma_f32_16x16x32_bf16(a, vz, aZ, 0, 0, 0);
        aIN = __builtin_amdgcn_mfma_f32_16x16x32_bf16(a, vn, aIN, 0, 0, 0);
      }
    }

    ushort* ho = histU + (size_t)(s + 1) * 65536;
    #pragma unroll
    for (int q = 0; q < 4; ++q) {
      float r = fsig(aR[q]);
      float z = fsig(aZ[q]);
      float n = ftanh(fmaf(r, aHN[q], aIN[q]));
      float h = fmaf(z, hp[q] - n, n);
      hp[q] = h;
      ho[(m0 + kqi * 4 + q) * 512 + col] = bf16r(h);
    }
    __syncthreads();     // all h-stores drained (syncthreads implies vmcnt(0))
    if (tid == 0) {
      __threadfence();   // flush XCD L2 so other XCDs see slot s+1
      __hip_atomic_store(fl + sub, s + 1, __ATOMIC_RELAXED,
                         __HIP_MEMORY_SCOPE_AGENT);
    }
  }
}

// dec_t = relu([H, hb_used] @ dec_W^T + dec_b): M=255*128, N=512, K=1024
__global__ __launch_bounds__(256)
void dec_mfma(const ushort* __restrict__ Hsb, const ushort* __restrict__ Ssb,
              const ushort* __restrict__ decWb, const float* __restrict__ decb,
              ushort* __restrict__ dectb) {
  const int t  = blockIdx.x;
  const int nb = blockIdx.y;
  const int wave = threadIdx.x >> 6, lane = threadIdx.x & 63;
  const int lr = lane & 15, kq = (lane >> 4) * 8;
  const int mrow = wave * 32;
  f32x4 acc[2][4] = {};
  for (int kc = 0; kc < 1024; kc += 32) {
    if (kc >= 512 && t == 254) break;
    const ushort* abase = (kc < 512)
        ? Hsb + ((size_t)t * BB) * RR + kc
        : Ssb + ((size_t)(253 - t) * BB) * RR + (kc - 512);
    bf16x8 a[2];
    #pragma unroll
    for (int mi = 0; mi < 2; ++mi)
      a[mi] = ld8(abase + (mrow + mi * 16 + lr) * RR + kq);
    bf16x8 bw[4];
    #pragma unroll
    for (int ni = 0; ni < 4; ++ni)
      bw[ni] = ld8(decWb + (size_t)(nb * 64 + ni * 16 + lr) * 1024 + kc + kq);
    #pragma unroll
    for (int mi = 0; mi < 2; ++mi)
      #pragma unroll
      for (int ni = 0; ni < 4; ++ni)
        acc[mi][ni] = __builtin_amdgcn_mfma_f32_16x16x32_bf16(a[mi], bw[ni], acc[mi][ni], 0, 0, 0);
  }
  #pragma unroll
  for (int mi = 0; mi < 2; ++mi)
    #pragma unroll
    for (int ni = 0; ni < 4; ++ni)
      #pragma unroll
      for (int q = 0; q < 4; ++q) {
        int row = t * BB + mrow + mi * 16 + (lane >> 4) * 4 + q;
        int n = nb * 64 + ni * 16 + lr;
        float v = fmaxf(acc[mi][ni][q] + decb[n], 0.0f);
        dectb[(size_t)row * 512 + n] = bf16r(v);
      }
}

// mean = dec_t @ mean_W^T + mean_b; loss += (mean - gt[t+1])^2
__global__ __launch_bounds__(256)
void mean_loss_mfma(const ushort* __restrict__ dectb, const ushort* __restrict__ meanWb,
                    const float* __restrict__ meanb, const float* __restrict__ gt,
                    float* __restrict__ out) {
  const int t = blockIdx.x;
  const int wave = threadIdx.x >> 6, lane = threadIdx.x & 63;
  const int lr = lane & 15, kq = (lane >> 4) * 8;
  const int mrow = wave * 32;
  f32x4 acc[2][4] = {};
  for (int kc = 0; kc < 512; kc += 32) {
    bf16x8 a[2];
    #pragma unroll
    for (int mi = 0; mi < 2; ++mi)
      a[mi] = ld8(dectb + ((size_t)t * BB + mrow + mi * 16 + lr) * 512 + kc + kq);
    bf16x8 bw[4];
    #pragma unroll
    for (int ni = 0; ni < 4; ++ni)
      bw[ni] = ld8(meanWb + (size_t)(ni * 16 + lr) * 512 + kc + kq);
    #pragma unroll
    for (int mi = 0; mi < 2; ++mi)
      #pragma unroll
      for (int ni = 0; ni < 4; ++ni)
        acc[mi][ni] = __builtin_amdgcn_mfma_f32_16x16x32_bf16(a[mi], bw[ni], acc[mi][ni], 0, 0, 0);
  }
  float lsum = 0.0f;
  #pragma unroll
  for (int mi = 0; mi < 2; ++mi)
    #pragma unroll
    for (int ni = 0; ni < 4; ++ni)
      #pragma unroll
      for (int q = 0; q < 4; ++q) {
        int b = mrow + mi * 16 + (lane >> 4) * 4 + q;
        int y = ni * 16 + lr;
        float m = acc[mi][ni][q] + meanb[y];
        float d = m - gt[(((size_t)(t + 1)) * BB + b) * 64 + y];
        lsum = fmaf(d, d, lsum);
      }
  __shared__ float red[256];
  red[threadIdx.x] = lsum;
  __syncthreads();
  for (int s2 = 128; s2 > 0; s2 >>= 1) {
    if (threadIdx.x < s2) red[threadIdx.x] += red[threadIdx.x + s2];
    __syncthreads();
  }
  if (threadIdx.x == 0) atomicAdd(out, red[0] * (1.0f / 32640.0f));
}

__global__ __launch_bounds__(256)
void cvt_bf16(const float* __restrict__ s, ushort* __restrict__ d, int n) {
  for (int i = blockIdx.x * 256 + threadIdx.x; i < n; i += gridDim.x * 256)
    d[i] = bf16r(s[i]);
}

__global__ __launch_bounds__(256)
void cvt_bf16_pad(const float* __restrict__ s, ushort* __restrict__ d,
                  int rows, int sc, int dc) {
  int n = rows * dc;
  for (int i = blockIdx.x * 256 + threadIdx.x; i < n; i += gridDim.x * 256) {
    int r = i / dc, c = i - r * dc;
    d[i] = (c < sc) ? bf16r(s[r * sc + c]) : (ushort)0;
  }
}

extern "C" void kernel_launch(void* const* d_in, const int* in_sizes, int n_in,
                              void* d_out, int out_size, void* d_ws, size_t ws_size,
                              hipStream_t stream) {
  const float* data = (const float*)d_in[0];
  const float* gt   = (const float*)d_in[1];
  RP p;
  p.Wi[0] = (const float*)d_in[2];  p.Wh[0] = (const float*)d_in[3];
  p.bi[0] = (const float*)d_in[4];  p.bh[0] = (const float*)d_in[5];
  p.Wi[2] = (const float*)d_in[6];  p.Wh[2] = (const float*)d_in[7];
  p.bi[2] = (const float*)d_in[8];  p.bh[2] = (const float*)d_in[9];
  p.Wi[1] = (const float*)d_in[10]; p.Wh[1] = (const float*)d_in[11];
  p.bi[1] = (const float*)d_in[12]; p.bh[1] = (const float*)d_in[13];
  p.Wi[3] = (const float*)d_in[14]; p.Wh[3] = (const float*)d_in[15];
  p.bi[3] = (const float*)d_in[16]; p.bh[3] = (const float*)d_in[17];
  const float* decW  = (const float*)d_in[18];
  const float* decb  = (const float*)d_in[19];
  const float* meanW = (const float*)d_in[20];
  const float* meanb = (const float*)d_in[21];

  // ws: flags(1KB) | hist[4] (4 x 33.55MB) | gtb | xpad | decWb | meanWb
  char* w = (char*)d_ws;
  int* flags = (int*)w;                  w += 1024;
  ushort* hist[4];
  for (int u2 = 0; u2 < 4; ++u2) { hist[u2] = (ushort*)w; w += (size_t)256 * BB * RR * 2; }
  ushort* gtb    = (ushort*)w; w += (size_t)256 * BB * 64 * 2;
  ushort* xpad   = (ushort*)w; w += (size_t)256 * BB * 96 * 2;
  ushort* decWb  = (ushort*)w; w += (size_t)512 * 1024 * 2;
  ushort* meanWb = (ushort*)w; w += (size_t)64 * 512 * 2;
  ushort* dectb  = hist[0];   // aliased: hist[0] dead after recur<2> finishes

  hipMemsetAsync(d_out, 0, sizeof(float), stream);
  hipMemsetAsync(flags, 0, 1024, stream);
  for (int u2 = 0; u2 < 4; ++u2)
    hipMemsetAsync(hist[u2], 0, (size_t)BB * RR * 2, stream);   // slot 0 = zeros

  cvt_bf16<<<512, 256, 0, stream>>>(gt, gtb, 256 * BB * 64);
  cvt_bf16_pad<<<512, 256, 0, stream>>>(data, xpad, 256 * BB, 65, 96);
  cvt_bf16<<<256, 256, 0, stream>>>(decW, decWb, 512 * 1024);
  cvt_bf16<<<64, 256, 0, stream>>>(meanW, meanWb, 64 * 512);

  p.gtb = gtb; p.xpad = xpad;
  for (int u2 = 0; u2 < 4; ++u2) p.hist[u2] = hist[u2];
  p.flags = flags;

  recur<0><<<dim3(128), dim3(256), 0, stream>>>(p);   // L0 units, 255 steps
  recur<2><<<dim3(128), dim3(256), 0, stream>>>(p);   // L1 units, 255 steps

  dec_mfma<<<dim3(255, 8), dim3(256), 0, stream>>>(hist[2] + 65536, hist[3] + 65536,
                                                   decWb, decb, dectb);
  mean_loss_mfma<<<dim3(255), dim3(256), 0, stream>>>(dectb, meanWb, meanb, gt,
                                                      (float*)d_out);
}

// Round 6
// 4001.474 us; speedup vs baseline: 2.2507x; 1.5087x over previous
//
#include <hip/hip_runtime.h>
#include <math.h>

#define BB 128
#define RR 512
#define NSTEP 255

typedef __attribute__((ext_vector_type(8))) __bf16 bf16x8;
typedef __attribute__((ext_vector_type(4))) float f32x4;

__device__ __forceinline__ bf16x8 ld8(const ushort* p) {
  return *reinterpret_cast<const bf16x8*>(p);
}
__device__ __forceinline__ ushort bf16r(float x) {
  unsigned u = __float_as_uint(x);
  u += 0x7fffu + ((u >> 16) & 1u);
  return (ushort)(u >> 16);
}
__device__ __forceinline__ float fsig(float x) { return 1.0f / (1.0f + __expf(-x)); }
__device__ __forceinline__ float ftanh(float x) {
  float e = __expf(-2.0f * fabsf(x));
  float r = (1.0f - e) / (1.0f + e);
  return copysignf(r, x);
}

// Merged persistent recurrence: 256 blocks = 4 units x 64 (32 j-tiles x 2
// m-halves), 1 block/CU (96KB LDS), 256 threads = 4 waves x m16.
// units: 0=fwd L0, 1=bwd L0, 2=fwd L1, 3=bwd L1.
// hist[u]: 256 slots of (128,512) bf16; slot 0 = zeros, h[s] at slot s+1
// (write-once slots -> no stale-copy hazard for consumers).
// Sync per step (r5 lesson: no consumer fence; r4 lesson: no acquire-per-poll):
//   producer: syncthreads -> tid0 {threadfence (wbl2), relaxed flag store}
//   consumer: wave0 polls own-unit flags >= s, wave1 polls parent flags >= s+1
//             (relaxed loads + ballot), NO fence (write-once addresses).
// One startup threadfence per block clears stale clean lines from the
// harness's ws re-poison / previous graph iterations.
struct RP {
  const ushort* gtb;     // (256,128,64) bf16
  const ushort* xpad;    // (256,128,96) bf16 (data padded 65->96)
  const float* Wh[4];    // (1536,512) fp32
  const float* Wi[4];    // u0:(1536,64) u1:(1536,65) u2,3:(1536,512) fp32
  const float* bi[4];
  const float* bh[4];
  ushort* hist[4];
  int* flags;            // [4][64]
};

__global__ __launch_bounds__(256, 1)
void recur_all(RP p) {
  const int bid = blockIdx.x;
  const int u = bid >> 6;                // 4 units x 64 blocks
  const int sub = bid & 63;
  const int jb = sub >> 1;               // 32 j-tiles
  const int mh = sub & 1;                // 2 m-halves
  const int j0 = jb * 16;
  const bool l1 = (u >= 2);
  const int tid = threadIdx.x;
  const int wave = tid >> 6, lane = tid & 63;
  const int lr = lane & 15, kqi = lane >> 4;
  const int kq = kqi * 8;
  const int m0 = mh * 64 + wave * 16;
  const int col = j0 + lr;

  // 96KB LDS: [0,48K) gh weight frags, [48K,...) gi weight frags.
  // frag layout: idx = it*3 + g; byte addr = idx*1024 + lane*16 (conflict-free).
  __shared__ ushort wl[49152];

  // ---- stage gh weights (one-time, fp32->bf16 in-kernel) ----
  {
    const float* Wh = p.Wh[u];
    for (int f = tid; f < 3072; f += 256) {
      int idx = f >> 6, l = f & 63;
      int it = idx / 3, g = idx - it * 3;
      const float* src = Wh + (size_t)(g * 512 + j0 + (l & 15)) * 512
                            + it * 32 + (l >> 4) * 8;
      float4 f0 = *(const float4*)src;
      float4 f1 = *(const float4*)(src + 4);
      uint4 v;
      v.x = bf16r(f0.x) | ((unsigned)bf16r(f0.y) << 16);
      v.y = bf16r(f0.z) | ((unsigned)bf16r(f0.w) << 16);
      v.z = bf16r(f1.x) | ((unsigned)bf16r(f1.y) << 16);
      v.w = bf16r(f1.z) | ((unsigned)bf16r(f1.w) << 16);
      *reinterpret_cast<uint4*>((char*)wl + idx * 1024 + l * 16) = v;
    }
  }
  // ---- stage gi weights ----
  const int xits = l1 ? 16 : (u == 0 ? 2 : 3);     // k-iters of 32
  const int xd   = l1 ? 512 : (u == 0 ? 64 : 65);  // true global cols
  const int xds  = l1 ? 512 : (u == 0 ? 64 : 96);  // input row stride
  {
    const float* Wi = p.Wi[u];
    for (int f = tid; f < xits * 3 * 64; f += 256) {
      int idx = f >> 6, l = f & 63;
      int it = idx / 3, g = idx - it * 3;
      const float* src = Wi + (size_t)(g * 512 + j0 + (l & 15)) * xd
                            + it * 32 + (l >> 4) * 8;
      float fv[8];
      #pragma unroll
      for (int e = 0; e < 8; ++e) {
        int cc = it * 32 + (l >> 4) * 8 + e;
        fv[e] = (cc < xd) ? src[e] : 0.0f;
      }
      uint4 v;
      v.x = bf16r(fv[0]) | ((unsigned)bf16r(fv[1]) << 16);
      v.y = bf16r(fv[2]) | ((unsigned)bf16r(fv[3]) << 16);
      v.z = bf16r(fv[4]) | ((unsigned)bf16r(fv[5]) << 16);
      v.w = bf16r(fv[6]) | ((unsigned)bf16r(fv[7]) << 16);
      *reinterpret_cast<uint4*>((char*)wl + 49152 + idx * 1024 + l * 16) = v;
    }
  }

  const float r0  = p.bi[u][col] + p.bh[u][col];
  const float z0  = p.bi[u][col + 512] + p.bh[u][col + 512];
  const float biN = p.bi[u][col + 1024];
  const float bhN = p.bh[u][col + 1024];
  // Startup fence: write-back + invalidate so no stale clean lines (from the
  // harness ws re-poison or a previous graph iteration) can serve h reads.
  if (tid == 0) __threadfence();
  __syncthreads();

  ushort* histU = p.hist[u];
  const ushort* histP = l1 ? p.hist[u - 2] : (const ushort*)0;
  int* fl = p.flags + u * 64;
  int* fp = l1 ? p.flags + (u - 2) * 64 : (int*)0;
  f32x4 hp = {0.0f, 0.0f, 0.0f, 0.0f};

  for (int s = 0; s < NSTEP; ++s) {
    // consumer waits (relaxed polls, no fence: write-once slot addresses)
    if (wave == 0 && s > 0) {
      for (;;) {
        int v = __hip_atomic_load(fl + lane, __ATOMIC_RELAXED,
                                  __HIP_MEMORY_SCOPE_AGENT);
        if (__ballot(v >= s) == ~0ull) break;
        __builtin_amdgcn_s_sleep(1);
      }
    }
    if (wave == 1 && l1) {
      for (;;) {
        int v = __hip_atomic_load(fp + lane, __ATOMIC_RELAXED,
                                  __HIP_MEMORY_SCOPE_AGENT);
        if (__ballot(v >= s + 1) == ~0ull) break;
        __builtin_amdgcn_s_sleep(1);
      }
    }
    __syncthreads();

    f32x4 aR  = {r0, r0, r0, r0};
    f32x4 aZ  = {z0, z0, z0, z0};
    f32x4 aIN = {biN, biN, biN, biN};
    f32x4 aHN = {bhN, bhN, bhN, bhN};

    const ushort* aS = histU + (size_t)s * 65536 + (m0 + lr) * 512 + kq;
    if (l1) {
      const ushort* aP = histP + (size_t)(s + 1) * 65536 + (m0 + lr) * 512 + kq;
      #pragma unroll 4
      for (int it = 0; it < 16; ++it) {
        bf16x8 a  = ld8(aS + it * 32);
        bf16x8 a2 = ld8(aP + it * 32);
        const char* wb = (const char*)wl + it * 3072 + lane * 16;
        bf16x8 wr = *(const bf16x8*)(wb);
        bf16x8 wz = *(const bf16x8*)(wb + 1024);
        bf16x8 wn = *(const bf16x8*)(wb + 2048);
        bf16x8 vr = *(const bf16x8*)(wb + 49152);
        bf16x8 vz = *(const bf16x8*)(wb + 50176);
        bf16x8 vn = *(const bf16x8*)(wb + 51200);
        aR  = __builtin_amdgcn_mfma_f32_16x16x32_bf16(a,  wr, aR, 0, 0, 0);
        aZ  = __builtin_amdgcn_mfma_f32_16x16x32_bf16(a,  wz, aZ, 0, 0, 0);
        aHN = __builtin_amdgcn_mfma_f32_16x16x32_bf16(a,  wn, aHN, 0, 0, 0);
        aR  = __builtin_amdgcn_mfma_f32_16x16x32_bf16(a2, vr, aR, 0, 0, 0);
        aZ  = __builtin_amdgcn_mfma_f32_16x16x32_bf16(a2, vz, aZ, 0, 0, 0);
        aIN = __builtin_amdgcn_mfma_f32_16x16x32_bf16(a2, vn, aIN, 0, 0, 0);
      }
    } else {
      #pragma unroll 4
      for (int it = 0; it < 16; ++it) {
        bf16x8 a = ld8(aS + it * 32);
        const char* wb = (const char*)wl + it * 3072 + lane * 16;
        bf16x8 wr = *(const bf16x8*)(wb);
        bf16x8 wz = *(const bf16x8*)(wb + 1024);
        bf16x8 wn = *(const bf16x8*)(wb + 2048);
        aR  = __builtin_amdgcn_mfma_f32_16x16x32_bf16(a, wr, aR, 0, 0, 0);
        aZ  = __builtin_amdgcn_mfma_f32_16x16x32_bf16(a, wz, aZ, 0, 0, 0);
        aHN = __builtin_amdgcn_mfma_f32_16x16x32_bf16(a, wn, aHN, 0, 0, 0);
      }
      const ushort* x = (u == 0) ? p.gtb + (size_t)s * BB * 64
                                 : p.xpad + (size_t)(255 - s) * BB * 96;
      const ushort* xA = x + (m0 + lr) * xds + kq;
      for (int it = 0; it < xits; ++it) {
        bf16x8 a = ld8(xA + it * 32);
        const char* wb = (const char*)wl + 49152 + it * 3072 + lane * 16;
        bf16x8 vr = *(const bf16x8*)(wb);
        bf16x8 vz = *(const bf16x8*)(wb + 1024);
        bf16x8 vn = *(const bf16x8*)(wb + 2048);
        aR  = __builtin_amdgcn_mfma_f32_16x16x32_bf16(a, vr, aR, 0, 0, 0);
        aZ  = __builtin_amdgcn_mfma_f32_16x16x32_bf16(a, vz, aZ, 0, 0, 0);
        aIN = __builtin_amdgcn_mfma_f32_16x16x32_bf16(a, vn, aIN, 0, 0, 0);
      }
    }

    ushort* ho = histU + (size_t)(s + 1) * 65536;
    #pragma unroll
    for (int q = 0; q < 4; ++q) {
      float r = fsig(aR[q]);
      float z = fsig(aZ[q]);
      float n = ftanh(fmaf(r, aHN[q], aIN[q]));
      float h = fmaf(z, hp[q] - n, n);
      hp[q] = h;
      ho[(m0 + kqi * 4 + q) * 512 + col] = bf16r(h);
    }
    __syncthreads();     // drains all waves' h stores
    if (tid == 0) {
      __threadfence();   // wbl2: push slot s+1 to the coherent point
      __hip_atomic_store(fl + sub, s + 1, __ATOMIC_RELAXED,
                         __HIP_MEMORY_SCOPE_AGENT);
    }
  }
}

// dec_t = relu([H, hb_used] @ dec_W^T + dec_b): M=255*128, N=512, K=1024
__global__ __launch_bounds__(256)
void dec_mfma(const ushort* __restrict__ Hsb, const ushort* __restrict__ Ssb,
              const ushort* __restrict__ decWb, const float* __restrict__ decb,
              ushort* __restrict__ dectb) {
  const int t  = blockIdx.x;
  const int nb = blockIdx.y;
  const int wave = threadIdx.x >> 6, lane = threadIdx.x & 63;
  const int lr = lane & 15, kq = (lane >> 4) * 8;
  const int mrow = wave * 32;
  f32x4 acc[2][4] = {};
  for (int kc = 0; kc < 1024; kc += 32) {
    if (kc >= 512 && t == 254) break;
    const ushort* abase = (kc < 512)
        ? Hsb + ((size_t)t * BB) * RR + kc
        : Ssb + ((size_t)(253 - t) * BB) * RR + (kc - 512);
    bf16x8 a[2];
    #pragma unroll
    for (int mi = 0; mi < 2; ++mi)
      a[mi] = ld8(abase + (mrow + mi * 16 + lr) * RR + kq);
    bf16x8 bw[4];
    #pragma unroll
    for (int ni = 0; ni < 4; ++ni)
      bw[ni] = ld8(decWb + (size_t)(nb * 64 + ni * 16 + lr) * 1024 + kc + kq);
    #pragma unroll
    for (int mi = 0; mi < 2; ++mi)
      #pragma unroll
      for (int ni = 0; ni < 4; ++ni)
        acc[mi][ni] = __builtin_amdgcn_mfma_f32_16x16x32_bf16(a[mi], bw[ni], acc[mi][ni], 0, 0, 0);
  }
  #pragma unroll
  for (int mi = 0; mi < 2; ++mi)
    #pragma unroll
    for (int ni = 0; ni < 4; ++ni)
      #pragma unroll
      for (int q = 0; q < 4; ++q) {
        int row = t * BB + mrow + mi * 16 + (lane >> 4) * 4 + q;
        int n = nb * 64 + ni * 16 + lr;
        float v = fmaxf(acc[mi][ni][q] + decb[n], 0.0f);
        dectb[(size_t)row * 512 + n] = bf16r(v);
      }
}

// mean = dec_t @ mean_W^T + mean_b; loss += (mean - gt[t+1])^2
__global__ __launch_bounds__(256)
void mean_loss_mfma(const ushort* __restrict__ dectb, const ushort* __restrict__ meanWb,
                    const float* __restrict__ meanb, const float* __restrict__ gt,
                    float* __restrict__ out) {
  const int t = blockIdx.x;
  const int wave = threadIdx.x >> 6, lane = threadIdx.x & 63;
  const int lr = lane & 15, kq = (lane >> 4) * 8;
  const int mrow = wave * 32;
  f32x4 acc[2][4] = {};
  for (int kc = 0; kc < 512; kc += 32) {
    bf16x8 a[2];
    #pragma unroll
    for (int mi = 0; mi < 2; ++mi)
      a[mi] = ld8(dectb + ((size_t)t * BB + mrow + mi * 16 + lr) * 512 + kc + kq);
    bf16x8 bw[4];
    #pragma unroll
    for (int ni = 0; ni < 4; ++ni)
      bw[ni] = ld8(meanWb + (size_t)(ni * 16 + lr) * 512 + kc + kq);
    #pragma unroll
    for (int mi = 0; mi < 2; ++mi)
      #pragma unroll
      for (int ni = 0; ni < 4; ++ni)
        acc[mi][ni] = __builtin_amdgcn_mfma_f32_16x16x32_bf16(a[mi], bw[ni], acc[mi][ni], 0, 0, 0);
  }
  float lsum = 0.0f;
  #pragma unroll
  for (int mi = 0; mi < 2; ++mi)
    #pragma unroll
    for (int ni = 0; ni < 4; ++ni)
      #pragma unroll
      for (int q = 0; q < 4; ++q) {
        int b = mrow + mi * 16 + (lane >> 4) * 4 + q;
        int y = ni * 16 + lr;
        float m = acc[mi][ni][q] + meanb[y];
        float d = m - gt[(((size_t)(t + 1)) * BB + b) * 64 + y];
        lsum = fmaf(d, d, lsum);
      }
  __shared__ float red[256];
  red[threadIdx.x] = lsum;
  __syncthreads();
  for (int s2 = 128; s2 > 0; s2 >>= 1) {
    if (threadIdx.x < s2) red[threadIdx.x] += red[threadIdx.x + s2];
    __syncthreads();
  }
  if (threadIdx.x == 0) atomicAdd(out, red[0] * (1.0f / 32640.0f));
}

__global__ __launch_bounds__(256)
void cvt_bf16(const float* __restrict__ s, ushort* __restrict__ d, int n) {
  for (int i = blockIdx.x * 256 + threadIdx.x; i < n; i += gridDim.x * 256)
    d[i] = bf16r(s[i]);
}

__global__ __launch_bounds__(256)
void cvt_bf16_pad(const float* __restrict__ s, ushort* __restrict__ d,
                  int rows, int sc, int dc) {
  int n = rows * dc;
  for (int i = blockIdx.x * 256 + threadIdx.x; i < n; i += gridDim.x * 256) {
    int r = i / dc, c = i - r * dc;
    d[i] = (c < sc) ? bf16r(s[r * sc + c]) : (ushort)0;
  }
}

extern "C" void kernel_launch(void* const* d_in, const int* in_sizes, int n_in,
                              void* d_out, int out_size, void* d_ws, size_t ws_size,
                              hipStream_t stream) {
  const float* data = (const float*)d_in[0];
  const float* gt   = (const float*)d_in[1];
  RP p;
  p.Wi[0] = (const float*)d_in[2];  p.Wh[0] = (const float*)d_in[3];
  p.bi[0] = (const float*)d_in[4];  p.bh[0] = (const float*)d_in[5];
  p.Wi[2] = (const float*)d_in[6];  p.Wh[2] = (const float*)d_in[7];
  p.bi[2] = (const float*)d_in[8];  p.bh[2] = (const float*)d_in[9];
  p.Wi[1] = (const float*)d_in[10]; p.Wh[1] = (const float*)d_in[11];
  p.bi[1] = (const float*)d_in[12]; p.bh[1] = (const float*)d_in[13];
  p.Wi[3] = (const float*)d_in[14]; p.Wh[3] = (const float*)d_in[15];
  p.bi[3] = (const float*)d_in[16]; p.bh[3] = (const float*)d_in[17];
  const float* decW  = (const float*)d_in[18];
  const float* decb  = (const float*)d_in[19];
  const float* meanW = (const float*)d_in[20];
  const float* meanb = (const float*)d_in[21];

  // ws: flags(1KB) | hist[4] (4 x 33.55MB) | gtb | xpad | decWb | meanWb
  char* w = (char*)d_ws;
  int* flags = (int*)w;                  w += 1024;
  ushort* hist[4];
  for (int u2 = 0; u2 < 4; ++u2) { hist[u2] = (ushort*)w; w += (size_t)256 * BB * RR * 2; }
  ushort* gtb    = (ushort*)w; w += (size_t)256 * BB * 64 * 2;
  ushort* xpad   = (ushort*)w; w += (size_t)256 * BB * 96 * 2;
  ushort* decWb  = (ushort*)w; w += (size_t)512 * 1024 * 2;
  ushort* meanWb = (ushort*)w; w += (size_t)64 * 512 * 2;
  ushort* dectb  = hist[0];   // aliased: hist[0] dead after recur_all finishes

  hipMemsetAsync(d_out, 0, sizeof(float), stream);
  hipMemsetAsync(flags, 0, 1024, stream);
  for (int u2 = 0; u2 < 4; ++u2)
    hipMemsetAsync(hist[u2], 0, (size_t)BB * RR * 2, stream);   // slot 0 = zeros

  cvt_bf16<<<512, 256, 0, stream>>>(gt, gtb, 256 * BB * 64);
  cvt_bf16_pad<<<512, 256, 0, stream>>>(data, xpad, 256 * BB, 65, 96);
  cvt_bf16<<<256, 256, 0, stream>>>(decW, decWb, 512 * 1024);
  cvt_bf16<<<64, 256, 0, stream>>>(meanW, meanWb, 64 * 512);

  p.gtb = gtb; p.xpad = xpad;
  for (int u2 = 0; u2 < 4; ++u2) p.hist[u2] = hist[u2];
  p.flags = flags;

  recur_all<<<dim3(256), dim3(256), 0, stream>>>(p);   // all 4 units, pipelined

  dec_mfma<<<dim3(255, 8), dim3(256), 0, stream>>>(hist[2] + 65536, hist[3] + 65536,
                                                   decWb, decb, dectb);
  mean_loss_mfma<<<dim3(255), dim3(256), 0, stream>>>(dectb, meanWb, meanb, gt,
                                                      (float*)d_out);
}

// Round 7
// 2255.433 us; speedup vs baseline: 3.9931x; 1.7741x over previous
//
#include <hip/hip_runtime.h>
#include <math.h>

#define BB 128
#define RR 512
#define NSTEP 255

typedef __attribute__((ext_vector_type(8))) __bf16 bf16x8;
typedef __attribute__((ext_vector_type(4))) float f32x4;

__device__ __forceinline__ bf16x8 ld8(const ushort* p) {
  return *reinterpret_cast<const bf16x8*>(p);
}
__device__ __forceinline__ ushort bf16r(float x) {
  unsigned u = __float_as_uint(x);
  u += 0x7fffu + ((u >> 16) & 1u);
  return (ushort)(u >> 16);
}
__device__ __forceinline__ float fsig(float x) { return 1.0f / (1.0f + __expf(-x)); }
__device__ __forceinline__ float ftanh(float x) {
  float e = __expf(-2.0f * fabsf(x));
  float r = (1.0f - e) / (1.0f + e);
  return copysignf(r, x);
}

// Merged persistent recurrence: 256 blocks = 4 units x 64 (32 j-tiles x 2
// m-halves), 1 block/CU (96KB LDS), 256 threads = 4 waves x m16.
// unit = bid & 3 -> unit's blocks land on XCDs {u, u+4} under round-robin
// dispatch (perf heuristic only).
// hist[u]: 256 slots of (128,512) bf16; slot 0 = zeros, h[s] at slot s+1
// (write-once slots). h published via sc1 (agent-relaxed) stores -> no
// per-step wbl2 fence (r6 lesson: per-step threadfence was ~13us/step).
// Sync: producer syncthreads (implicit vmcnt(0)) -> tid0 relaxed-agent flag
// store. Consumers poll 64 flags with relaxed-agent loads + ballot, no fence.
// L1 ordering hides own-unit exchange latency behind the gi GEMM:
//   poll parent h0[s] -> gi = h0[s]@Wi -> poll own h1[s-1] -> gh -> gates.
// L0 prefetches its small input projection into registers after flagging.
struct RP {
  const ushort* gtb;     // (256,128,64) bf16
  const ushort* xpad;    // (256,128,96) bf16 (data padded 65->96)
  const float* Wh[4];    // (1536,512) fp32
  const float* Wi[4];    // u0:(1536,64) u1:(1536,65) u2,3:(1536,512) fp32
  const float* bi[4];
  const float* bh[4];
  ushort* hist[4];
  int* flags;            // [4][64]
};

__global__ __launch_bounds__(256, 1)
void recur_all(RP p) {
  const int bid = blockIdx.x;
  const int u = bid & 3;                 // XCD-affine unit mapping
  const int sub = bid >> 2;              // 0..63 within unit
  const int jb = sub >> 1;               // 32 j-tiles
  const int mh = sub & 1;                // 2 m-halves
  const int j0 = jb * 16;
  const bool l1 = (u >= 2);
  const int tid = threadIdx.x;
  const int wave = tid >> 6, lane = tid & 63;
  const int lr = lane & 15, kqi = lane >> 4;
  const int kq = kqi * 8;
  const int m0 = mh * 64 + wave * 16;
  const int col = j0 + lr;

  // 96KB LDS: [0,48K) gh weight frags, [48K,...) gi weight frags.
  // frag layout: idx = it*3 + g; byte addr = idx*1024 + lane*16 (conflict-free).
  __shared__ ushort wl[49152];

  // ---- stage gh weights (one-time, fp32->bf16 in-kernel) ----
  {
    const float* Wh = p.Wh[u];
    for (int f = tid; f < 3072; f += 256) {
      int idx = f >> 6, l = f & 63;
      int it = idx / 3, g = idx - it * 3;
      const float* src = Wh + (size_t)(g * 512 + j0 + (l & 15)) * 512
                            + it * 32 + (l >> 4) * 8;
      float4 f0 = *(const float4*)src;
      float4 f1 = *(const float4*)(src + 4);
      uint4 v;
      v.x = bf16r(f0.x) | ((unsigned)bf16r(f0.y) << 16);
      v.y = bf16r(f0.z) | ((unsigned)bf16r(f0.w) << 16);
      v.z = bf16r(f1.x) | ((unsigned)bf16r(f1.y) << 16);
      v.w = bf16r(f1.z) | ((unsigned)bf16r(f1.w) << 16);
      *reinterpret_cast<uint4*>((char*)wl + idx * 1024 + l * 16) = v;
    }
  }
  // ---- stage gi weights ----
  const int xits = l1 ? 16 : (u == 0 ? 2 : 3);     // k-iters of 32
  const int xd   = l1 ? 512 : (u == 0 ? 64 : 65);  // true global cols
  const int xds  = l1 ? 512 : (u == 0 ? 64 : 96);  // input row stride
  {
    const float* Wi = p.Wi[u];
    for (int f = tid; f < xits * 3 * 64; f += 256) {
      int idx = f >> 6, l = f & 63;
      int it = idx / 3, g = idx - it * 3;
      const float* src = Wi + (size_t)(g * 512 + j0 + (l & 15)) * xd
                            + it * 32 + (l >> 4) * 8;
      float fv[8];
      #pragma unroll
      for (int e = 0; e < 8; ++e) {
        int cc = it * 32 + (l >> 4) * 8 + e;
        fv[e] = (cc < xd) ? src[e] : 0.0f;
      }
      uint4 v;
      v.x = bf16r(fv[0]) | ((unsigned)bf16r(fv[1]) << 16);
      v.y = bf16r(fv[2]) | ((unsigned)bf16r(fv[3]) << 16);
      v.z = bf16r(fv[4]) | ((unsigned)bf16r(fv[5]) << 16);
      v.w = bf16r(fv[6]) | ((unsigned)bf16r(fv[7]) << 16);
      *reinterpret_cast<uint4*>((char*)wl + 49152 + idx * 1024 + l * 16) = v;
    }
  }

  const float r0  = p.bi[u][col] + p.bh[u][col];
  const float z0  = p.bi[u][col + 512] + p.bh[u][col + 512];
  const float biN = p.bi[u][col + 1024];
  const float bhN = p.bh[u][col + 1024];
  if (tid == 0) __threadfence();   // one-time: clear any stale lines
  __syncthreads();

  ushort* histU = p.hist[u];
  const ushort* histP = l1 ? p.hist[u - 2] : (const ushort*)0;
  int* fl = p.flags + u * 64;
  int* fp = l1 ? p.flags + (u - 2) * 64 : (int*)0;
  f32x4 hp = {0.0f, 0.0f, 0.0f, 0.0f};

  // L0 input-projection register pipeline (computed one step ahead)
  f32x4 giR = {}, giZ = {}, giIN = {};
  auto gi_l0 = [&](int s2) {
    giR = (f32x4){0.f, 0.f, 0.f, 0.f};
    giZ = (f32x4){0.f, 0.f, 0.f, 0.f};
    giIN = (f32x4){biN, biN, biN, biN};
    const ushort* x = (u == 0) ? p.gtb + (size_t)s2 * BB * 64
                               : p.xpad + (size_t)(255 - s2) * BB * 96;
    const ushort* xA = x + (m0 + lr) * xds + kq;
    for (int it = 0; it < xits; ++it) {
      bf16x8 a = ld8(xA + it * 32);
      const char* wb = (const char*)wl + 49152 + it * 3072 + lane * 16;
      bf16x8 vr = *(const bf16x8*)(wb);
      bf16x8 vz = *(const bf16x8*)(wb + 1024);
      bf16x8 vn = *(const bf16x8*)(wb + 2048);
      giR  = __builtin_amdgcn_mfma_f32_16x16x32_bf16(a, vr, giR, 0, 0, 0);
      giZ  = __builtin_amdgcn_mfma_f32_16x16x32_bf16(a, vz, giZ, 0, 0, 0);
      giIN = __builtin_amdgcn_mfma_f32_16x16x32_bf16(a, vn, giIN, 0, 0, 0);
    }
  };
  if (!l1) gi_l0(0);

  auto poll = [&](int* f, int tgt) {
    for (;;) {
      int v = __hip_atomic_load(f + lane, __ATOMIC_RELAXED,
                                __HIP_MEMORY_SCOPE_AGENT);
      if (__ballot(v >= tgt) == ~0ull) break;
      __builtin_amdgcn_s_sleep(1);
    }
  };

  for (int s = 0; s < NSTEP; ++s) {
    f32x4 aR  = {r0, r0, r0, r0};
    f32x4 aZ  = {z0, z0, z0, z0};
    f32x4 aIN = {biN, biN, biN, biN};
    f32x4 aHN = {bhN, bhN, bhN, bhN};

    const ushort* aS = histU + (size_t)s * 65536 + (m0 + lr) * 512 + kq;
    if (l1) {
      // (1) parent data (L0 runs ahead -> short poll)
      if (wave == 0) poll(fp, s + 1);
      __syncthreads();
      // (2) gi GEMM from parent h0[s] — hides own-unit exchange latency
      const ushort* aP = histP + (size_t)(s + 1) * 65536 + (m0 + lr) * 512 + kq;
      #pragma unroll 4
      for (int it = 0; it < 16; ++it) {
        bf16x8 a2 = ld8(aP + it * 32);
        const char* wb = (const char*)wl + 49152 + it * 3072 + lane * 16;
        bf16x8 vr = *(const bf16x8*)(wb);
        bf16x8 vz = *(const bf16x8*)(wb + 1024);
        bf16x8 vn = *(const bf16x8*)(wb + 2048);
        aR  = __builtin_amdgcn_mfma_f32_16x16x32_bf16(a2, vr, aR, 0, 0, 0);
        aZ  = __builtin_amdgcn_mfma_f32_16x16x32_bf16(a2, vz, aZ, 0, 0, 0);
        aIN = __builtin_amdgcn_mfma_f32_16x16x32_bf16(a2, vn, aIN, 0, 0, 0);
      }
      // (3) own-unit h1[s-1] (likely already flagged during gi)
      if (wave == 0 && s > 0) poll(fl, s);
      __syncthreads();
      // (4) gh GEMM
      #pragma unroll 4
      for (int it = 0; it < 16; ++it) {
        bf16x8 a = ld8(aS + it * 32);
        const char* wb = (const char*)wl + it * 3072 + lane * 16;
        bf16x8 wr = *(const bf16x8*)(wb);
        bf16x8 wz = *(const bf16x8*)(wb + 1024);
        bf16x8 wn = *(const bf16x8*)(wb + 2048);
        aR  = __builtin_amdgcn_mfma_f32_16x16x32_bf16(a, wr, aR, 0, 0, 0);
        aZ  = __builtin_amdgcn_mfma_f32_16x16x32_bf16(a, wz, aZ, 0, 0, 0);
        aHN = __builtin_amdgcn_mfma_f32_16x16x32_bf16(a, wn, aHN, 0, 0, 0);
      }
    } else {
      if (wave == 0 && s > 0) poll(fl, s);
      __syncthreads();
      #pragma unroll 4
      for (int it = 0; it < 16; ++it) {
        bf16x8 a = ld8(aS + it * 32);
        const char* wb = (const char*)wl + it * 3072 + lane * 16;
        bf16x8 wr = *(const bf16x8*)(wb);
        bf16x8 wz = *(const bf16x8*)(wb + 1024);
        bf16x8 wn = *(const bf16x8*)(wb + 2048);
        aR  = __builtin_amdgcn_mfma_f32_16x16x32_bf16(a, wr, aR, 0, 0, 0);
        aZ  = __builtin_amdgcn_mfma_f32_16x16x32_bf16(a, wz, aZ, 0, 0, 0);
        aHN = __builtin_amdgcn_mfma_f32_16x16x32_bf16(a, wn, aHN, 0, 0, 0);
      }
    }

    ushort* ho = histU + (size_t)(s + 1) * 65536;
    #pragma unroll
    for (int q = 0; q < 4; ++q) {
      float r, z, n;
      if (l1) {
        r = fsig(aR[q]);
        z = fsig(aZ[q]);
        n = ftanh(fmaf(r, aHN[q], aIN[q]));
      } else {
        r = fsig(aR[q] + giR[q]);
        z = fsig(aZ[q] + giZ[q]);
        n = ftanh(fmaf(r, aHN[q], giIN[q]));
      }
      float h = fmaf(z, hp[q] - n, n);
      hp[q] = h;
      // sc1 (agent-relaxed) store: write-through to coherence point,
      // no producer wbl2 fence needed before the flag.
      __hip_atomic_store(&ho[(m0 + kqi * 4 + q) * 512 + col], bf16r(h),
                         __ATOMIC_RELAXED, __HIP_MEMORY_SCOPE_AGENT);
    }
    __syncthreads();     // implicit vmcnt(0): all h stores completed
    if (tid == 0)
      __hip_atomic_store(fl + sub, s + 1, __ATOMIC_RELAXED,
                         __HIP_MEMORY_SCOPE_AGENT);
    // L0: prefetch next step's input projection while peers finish+publish
    if (!l1 && s + 1 < NSTEP) gi_l0(s + 1);
  }
}

// dec_t = relu([H, hb_used] @ dec_W^T + dec_b): M=255*128, N=512, K=1024
__global__ __launch_bounds__(256)
void dec_mfma(const ushort* __restrict__ Hsb, const ushort* __restrict__ Ssb,
              const ushort* __restrict__ decWb, const float* __restrict__ decb,
              ushort* __restrict__ dectb) {
  const int t  = blockIdx.x;
  const int nb = blockIdx.y;
  const int wave = threadIdx.x >> 6, lane = threadIdx.x & 63;
  const int lr = lane & 15, kq = (lane >> 4) * 8;
  const int mrow = wave * 32;
  f32x4 acc[2][4] = {};
  for (int kc = 0; kc < 1024; kc += 32) {
    if (kc >= 512 && t == 254) break;
    const ushort* abase = (kc < 512)
        ? Hsb + ((size_t)t * BB) * RR + kc
        : Ssb + ((size_t)(253 - t) * BB) * RR + (kc - 512);
    bf16x8 a[2];
    #pragma unroll
    for (int mi = 0; mi < 2; ++mi)
      a[mi] = ld8(abase + (mrow + mi * 16 + lr) * RR + kq);
    bf16x8 bw[4];
    #pragma unroll
    for (int ni = 0; ni < 4; ++ni)
      bw[ni] = ld8(decWb + (size_t)(nb * 64 + ni * 16 + lr) * 1024 + kc + kq);
    #pragma unroll
    for (int mi = 0; mi < 2; ++mi)
      #pragma unroll
      for (int ni = 0; ni < 4; ++ni)
        acc[mi][ni] = __builtin_amdgcn_mfma_f32_16x16x32_bf16(a[mi], bw[ni], acc[mi][ni], 0, 0, 0);
  }
  #pragma unroll
  for (int mi = 0; mi < 2; ++mi)
    #pragma unroll
    for (int ni = 0; ni < 4; ++ni)
      #pragma unroll
      for (int q = 0; q < 4; ++q) {
        int row = t * BB + mrow + mi * 16 + (lane >> 4) * 4 + q;
        int n = nb * 64 + ni * 16 + lr;
        float v = fmaxf(acc[mi][ni][q] + decb[n], 0.0f);
        dectb[(size_t)row * 512 + n] = bf16r(v);
      }
}

// mean = dec_t @ mean_W^T + mean_b; loss += (mean - gt[t+1])^2
__global__ __launch_bounds__(256)
void mean_loss_mfma(const ushort* __restrict__ dectb, const ushort* __restrict__ meanWb,
                    const float* __restrict__ meanb, const float* __restrict__ gt,
                    float* __restrict__ out) {
  const int t = blockIdx.x;
  const int wave = threadIdx.x >> 6, lane = threadIdx.x & 63;
  const int lr = lane & 15, kq = (lane >> 4) * 8;
  const int mrow = wave * 32;
  f32x4 acc[2][4] = {};
  for (int kc = 0; kc < 512; kc += 32) {
    bf16x8 a[2];
    #pragma unroll
    for (int mi = 0; mi < 2; ++mi)
      a[mi] = ld8(dectb + ((size_t)t * BB + mrow + mi * 16 + lr) * 512 + kc + kq);
    bf16x8 bw[4];
    #pragma unroll
    for (int ni = 0; ni < 4; ++ni)
      bw[ni] = ld8(meanWb + (size_t)(ni * 16 + lr) * 512 + kc + kq);
    #pragma unroll
    for (int mi = 0; mi < 2; ++mi)
      #pragma unroll
      for (int ni = 0; ni < 4; ++ni)
        acc[mi][ni] = __builtin_amdgcn_mfma_f32_16x16x32_bf16(a[mi], bw[ni], acc[mi][ni], 0, 0, 0);
  }
  float lsum = 0.0f;
  #pragma unroll
  for (int mi = 0; mi < 2; ++mi)
    #pragma unroll
    for (int ni = 0; ni < 4; ++ni)
      #pragma unroll
      for (int q = 0; q < 4; ++q) {
        int b = mrow + mi * 16 + (lane >> 4) * 4 + q;
        int y = ni * 16 + lr;
        float m = acc[mi][ni][q] + meanb[y];
        float d = m - gt[(((size_t)(t + 1)) * BB + b) * 64 + y];
        lsum = fmaf(d, d, lsum);
      }
  __shared__ float red[256];
  red[threadIdx.x] = lsum;
  __syncthreads();
  for (int s2 = 128; s2 > 0; s2 >>= 1) {
    if (threadIdx.x < s2) red[threadIdx.x] += red[threadIdx.x + s2];
    __syncthreads();
  }
  if (threadIdx.x == 0) atomicAdd(out, red[0] * (1.0f / 32640.0f));
}

__global__ __launch_bounds__(256)
void cvt_bf16(const float* __restrict__ s, ushort* __restrict__ d, int n) {
  for (int i = blockIdx.x * 256 + threadIdx.x; i < n; i += gridDim.x * 256)
    d[i] = bf16r(s[i]);
}

__global__ __launch_bounds__(256)
void cvt_bf16_pad(const float* __restrict__ s, ushort* __restrict__ d,
                  int rows, int sc, int dc) {
  int n = rows * dc;
  for (int i = blockIdx.x * 256 + threadIdx.x; i < n; i += gridDim.x * 256) {
    int r = i / dc, c = i - r * dc;
    d[i] = (c < sc) ? bf16r(s[r * sc + c]) : (ushort)0;
  }
}

extern "C" void kernel_launch(void* const* d_in, const int* in_sizes, int n_in,
                              void* d_out, int out_size, void* d_ws, size_t ws_size,
                              hipStream_t stream) {
  const float* data = (const float*)d_in[0];
  const float* gt   = (const float*)d_in[1];
  RP p;
  p.Wi[0] = (const float*)d_in[2];  p.Wh[0] = (const float*)d_in[3];
  p.bi[0] = (const float*)d_in[4];  p.bh[0] = (const float*)d_in[5];
  p.Wi[2] = (const float*)d_in[6];  p.Wh[2] = (const float*)d_in[7];
  p.bi[2] = (const float*)d_in[8];  p.bh[2] = (const float*)d_in[9];
  p.Wi[1] = (const float*)d_in[10]; p.Wh[1] = (const float*)d_in[11];
  p.bi[1] = (const float*)d_in[12]; p.bh[1] = (const float*)d_in[13];
  p.Wi[3] = (const float*)d_in[14]; p.Wh[3] = (const float*)d_in[15];
  p.bi[3] = (const float*)d_in[16]; p.bh[3] = (const float*)d_in[17];
  const float* decW  = (const float*)d_in[18];
  const float* decb  = (const float*)d_in[19];
  const float* meanW = (const float*)d_in[20];
  const float* meanb = (const float*)d_in[21];

  // ws: flags(1KB) | hist[4] (4 x 33.55MB) | gtb | xpad | decWb | meanWb
  char* w = (char*)d_ws;
  int* flags = (int*)w;                  w += 1024;
  ushort* hist[4];
  for (int u2 = 0; u2 < 4; ++u2) { hist[u2] = (ushort*)w; w += (size_t)256 * BB * RR * 2; }
  ushort* gtb    = (ushort*)w; w += (size_t)256 * BB * 64 * 2;
  ushort* xpad   = (ushort*)w; w += (size_t)256 * BB * 96 * 2;
  ushort* decWb  = (ushort*)w; w += (size_t)512 * 1024 * 2;
  ushort* meanWb = (ushort*)w; w += (size_t)64 * 512 * 2;
  ushort* dectb  = hist[0];   // aliased: hist[0] dead after recur_all finishes

  hipMemsetAsync(d_out, 0, sizeof(float), stream);
  hipMemsetAsync(flags, 0, 1024, stream);
  for (int u2 = 0; u2 < 4; ++u2)
    hipMemsetAsync(hist[u2], 0, (size_t)BB * RR * 2, stream);   // slot 0 = zeros

  cvt_bf16<<<512, 256, 0, stream>>>(gt, gtb, 256 * BB * 64);
  cvt_bf16_pad<<<512, 256, 0, stream>>>(data, xpad, 256 * BB, 65, 96);
  cvt_bf16<<<256, 256, 0, stream>>>(decW, decWb, 512 * 1024);
  cvt_bf16<<<64, 256, 0, stream>>>(meanW, meanWb, 64 * 512);

  p.gtb = gtb; p.xpad = xpad;
  for (int u2 = 0; u2 < 4; ++u2) p.hist[u2] = hist[u2];
  p.flags = flags;

  recur_all<<<dim3(256), dim3(256), 0, stream>>>(p);   // all 4 units, pipelined

  dec_mfma<<<dim3(255, 8), dim3(256), 0, stream>>>(hist[2] + 65536, hist[3] + 65536,
                                                   decWb, decb, dectb);
  mean_loss_mfma<<<dim3(255), dim3(256), 0, stream>>>(dectb, meanWb, meanb, gt,
                                                      (float*)d_out);
}